// Round 5
// baseline (372.775 us; speedup 1.0000x reference)
//
#include <hip/hip_runtime.h>
#include <hip/hip_fp16.h>

#define N_TOK 8192
#define DMODEL 1024
#define HDIM 2048
#define NEXP 8
#define NGU (2 * HDIM)              // 4096 interleaved gate/up cols
#define NPAD (N_TOK + NEXP * 128)   // 9216 (expert segments padded to x128)
#define NT 72                       // 128-row tiles

typedef _Float16 f16;
typedef _Float16 f16x8 __attribute__((ext_vector_type(8)));
typedef float f32x4 __attribute__((ext_vector_type(4)));

#define SBAR() __builtin_amdgcn_sched_barrier(0)
#define BARRIER() do { __builtin_amdgcn_s_barrier(); SBAR(); } while (0)
#define WAIT_LGKM(n) do { asm volatile("s_waitcnt lgkmcnt(" #n ")" ::: "memory"); SBAR(); } while (0)
#define WAIT_VM(n)  do { asm volatile("s_waitcnt vmcnt(" #n ")" ::: "memory"); SBAR(); } while (0)

__device__ __forceinline__ void gload16(const void* g, void* l) {
    __builtin_amdgcn_global_load_lds(
        (const __attribute__((address_space(1))) void*)g,
        (__attribute__((address_space(3))) void*)l, 16, 0, 0);
}

// ---- aux kernels ----
__global__ void k_plan(const int* __restrict__ ids, int* __restrict__ cursor,
                       int* __restrict__ tile_map) {
    __shared__ int hist[NEXP];
    const int tid = threadIdx.x;
    if (tid < NEXP) hist[tid] = 0;
    __syncthreads();
    for (int t = tid; t < N_TOK; t += 256) atomicAdd(&hist[ids[t]], 1);
    __syncthreads();
    if (tid == 0) {
        int pos = 0, tile = 0;
        for (int e = 0; e < NEXP; ++e) {
            cursor[e] = pos;
            const int nt = (hist[e] + 127) >> 7;
            for (int i = 0; i < nt; ++i) tile_map[tile++] = e;
            pos += nt * 128;
        }
        for (; tile < NT; ++tile) tile_map[tile] = -1;
    }
}

__global__ void k_scatter(const int* __restrict__ ids, int* __restrict__ cursor,
                          int* __restrict__ perm) {
    const int t = blockIdx.x * 256 + threadIdx.x;
    if (t < N_TOK) {
        const int pos = atomicAdd(&cursor[ids[t]], 1);
        perm[pos] = t;
    }
}

__global__ void k_cvt(const float* __restrict__ src, f16* __restrict__ dst) {
    const size_t i = (size_t)blockIdx.x * 256 + threadIdx.x;
    const float4* s = (const float4*)src + i * 2;
    const float4 a = s[0], b = s[1];
    f16x8 v;
    v[0] = (f16)a.x; v[1] = (f16)a.y; v[2] = (f16)a.z; v[3] = (f16)a.w;
    v[4] = (f16)b.x; v[5] = (f16)b.y; v[6] = (f16)b.z; v[7] = (f16)b.w;
    ((f16x8*)dst)[i] = v;
}

// gate/up -> interleaved f16 [E][4096][1024]; col c: h=(c>>5)*16+(c&15), bit4: up
__global__ void k_cvt_gu(const float* __restrict__ wg, const float* __restrict__ wu,
                         f16* __restrict__ wgu) {
    const int R = blockIdx.x;
    const int e = R >> 12, c = R & (NGU - 1);
    const int h = ((c >> 5) << 4) | (c & 15);
    const float* src = (((c >> 4) & 1) ? wu : wg) + ((size_t)e * HDIM + h) * DMODEL;
    f16* dst = wgu + (size_t)R * DMODEL;
    const int t = threadIdx.x;
    const float4* s = (const float4*)src + t * 2;
    const float4 a = s[0], b = s[1];
    f16x8 v;
    v[0] = (f16)a.x; v[1] = (f16)a.y; v[2] = (f16)a.z; v[3] = (f16)a.w;
    v[4] = (f16)b.x; v[5] = (f16)b.y; v[6] = (f16)b.z; v[7] = (f16)b.w;
    ((f16x8*)dst)[t] = v;
}

__global__ void k_gather(const float* __restrict__ x, const int* __restrict__ perm,
                         f16* __restrict__ xp) {
    const int row = blockIdx.x;
    const int tok = perm[row];
    const int c = threadIdx.x;
    f16x8 v;
#pragma unroll
    for (int j = 0; j < 8; ++j) v[j] = (f16)0.f;
    if (tok >= 0) {
        const float4* s = (const float4*)(x + (size_t)tok * DMODEL) + c * 2;
        const float4 a = s[0], b = s[1];
        v[0] = (f16)a.x; v[1] = (f16)a.y; v[2] = (f16)a.z; v[3] = (f16)a.w;
        v[4] = (f16)b.x; v[5] = (f16)b.y; v[6] = (f16)b.z; v[7] = (f16)b.w;
    }
    *((f16x8*)(xp + (size_t)row * DMODEL) + c) = v;
}

// ======== 128x128 core: 4 waves, BK=64, A via gload_lds ring-3, B reg-direct ====
// Per kt: [8 ds_read a] [stage A(kt+2): 4 gload_lds] vmcnt(16)=B(kt) ready,
// lgkm(4), MFMA mf0-1, lgkm(0), MFMA mf2-3, [load B(kt+2): 8 dwordx4] vmcnt(20)
// = A(kt+1) drained BEFORE barrier (cross-wave LDS rule), barrier, rotate.
// FIFO/wave: steady [B(kt),A(kt+1),B(kt+1)]+A(kt+2)=24 -> vm16 drains B(kt);
// +B(kt+2)=28? no: after vm16 -> 16, +B8=24 -> vm20 drains A(kt+1). Tail:
// kt==NKT-2: vm12/vm8; last kt: vm0.

#define STAGE_A(kk, slotoff) do {                                                     \
    _Pragma("unroll")                                                                 \
    for (int p = 0; p < 4; ++p)                                                       \
        gload16(ap[p] + (size_t)(kk) * 64, smem + (slotoff) + p * 4096 + wid * 1024); \
} while (0)

#define LOADB(BUF, kk) do {                                                           \
    _Pragma("unroll")                                                                 \
    for (int n = 0; n < 4; ++n)                                                       \
        _Pragma("unroll")                                                             \
        for (int ks = 0; ks < 2; ++ks)                                                \
            asm volatile("global_load_dwordx4 %0, %1, off"                            \
                         : "=v"(BUF[n][ks]) : "v"(bp[n][ks] + (size_t)(kk) * 64)      \
                         : "memory");                                                 \
} while (0)

#define KBODY(NKT_, ktv, BUF) do {                                                    \
    const int kt_ = (ktv);                                                            \
    char* aslot = smem + s_cur * 16384;                                               \
    f16x8 a[4][2];                                                                    \
    _Pragma("unroll")                                                                 \
    for (int mf = 0; mf < 4; ++mf) {                                                  \
        a[mf][0] = *(const f16x8*)(aslot + off_a[mf][0]);                             \
        a[mf][1] = *(const f16x8*)(aslot + off_a[mf][1]);                             \
    }                                                                                 \
    if (kt_ + 2 < NKT_) STAGE_A(kt_ + 2, s_n2 * 16384);                               \
    if (kt_ + 2 < NKT_) { WAIT_VM(16); }                                              \
    else if (kt_ == NKT_ - 2) { WAIT_VM(12); }                                        \
    else { WAIT_VM(0); }                                                              \
    WAIT_LGKM(4);                                                                     \
    __builtin_amdgcn_s_setprio(1);                                                    \
    _Pragma("unroll")                                                                 \
    for (int mi = 0; mi < 2; ++mi)                                                    \
        _Pragma("unroll")                                                             \
        for (int n = 0; n < 4; ++n) {                                                 \
            acc[mi][n] = __builtin_amdgcn_mfma_f32_16x16x32_f16(a[mi][0], BUF[n][0], acc[mi][n], 0, 0, 0); \
            acc[mi][n] = __builtin_amdgcn_mfma_f32_16x16x32_f16(a[mi][1], BUF[n][1], acc[mi][n], 0, 0, 0); \
        }                                                                             \
    __builtin_amdgcn_s_setprio(0);                                                    \
    WAIT_LGKM(0);                                                                     \
    __builtin_amdgcn_s_setprio(1);                                                    \
    _Pragma("unroll")                                                                 \
    for (int mi = 2; mi < 4; ++mi)                                                    \
        _Pragma("unroll")                                                             \
        for (int n = 0; n < 4; ++n) {                                                 \
            acc[mi][n] = __builtin_amdgcn_mfma_f32_16x16x32_f16(a[mi][0], BUF[n][0], acc[mi][n], 0, 0, 0); \
            acc[mi][n] = __builtin_amdgcn_mfma_f32_16x16x32_f16(a[mi][1], BUF[n][1], acc[mi][n], 0, 0, 0); \
        }                                                                             \
    __builtin_amdgcn_s_setprio(0);                                                    \
    if (kt_ + 2 < NKT_) { LOADB(BUF, kt_ + 2); WAIT_VM(20); }                         \
    else if (kt_ == NKT_ - 2) { WAIT_VM(8); }                                         \
    BARRIER();                                                                        \
    s_cur = (s_cur == 2) ? 0 : s_cur + 1;                                             \
    s_n2 = (s_n2 == 2) ? 0 : s_n2 + 1;                                                \
} while (0)

#define GCORE(NKT_, STRIDE_)                                                          \
    const int tid = threadIdx.x;                                                      \
    const int lane = tid & 63, wid = tid >> 6;                                        \
    const int wm = wid >> 1, wn = wid & 1;                                            \
    const int lrow = lane & 15, lk = lane >> 4;                                       \
    __shared__ char smem[49152];                                                      \
    const int scol = (lane & 7) ^ (lane >> 3);                                        \
    const f16* ap[4];                                                                 \
    _Pragma("unroll")                                                                 \
    for (int p = 0; p < 4; ++p)                                                       \
        ap[p] = asrc + (size_t)(p * 32 + wid * 8 + (lane >> 3)) * STRIDE_ + scol * 8; \
    const f16* bp[4][2];                                                              \
    _Pragma("unroll")                                                                 \
    for (int n = 0; n < 4; ++n)                                                       \
        _Pragma("unroll")                                                             \
        for (int ks = 0; ks < 2; ++ks)                                                \
            bp[n][ks] = bsrc + (size_t)(wn * 64 + n * 16 + lrow) * STRIDE_ + ks * 32 + lk * 8; \
    int off_a[4][2];                                                                  \
    _Pragma("unroll")                                                                 \
    for (int mf = 0; mf < 4; ++mf) {                                                  \
        const int rr = (wm * 64 + mf * 16 + lrow) * 128;                              \
        off_a[mf][0] = rr + ((lk ^ (lrow & 7)) * 16);                                 \
        off_a[mf][1] = rr + (((4 + lk) ^ (lrow & 7)) * 16);                           \
    }                                                                                 \
    f32x4 acc[4][4] = {};                                                             \
    f16x8 be[4][2], bo[4][2];                                                         \
    STAGE_A(0, 0); LOADB(be, 0); STAGE_A(1, 16384); LOADB(bo, 1);                     \
    WAIT_VM(20); BARRIER();                                                           \
    int s_cur = 0, s_n2 = 2;                                                          \
    _Pragma("unroll 1")                                                               \
    for (int kt = 0; kt < NKT_; kt += 2) {                                            \
        KBODY(NKT_, kt, be);                                                          \
        KBODY(NKT_, kt + 1, bo);                                                      \
    }

// ---- GEMM1 (xp @ wgu^T) + SwiGLU -> hidden ----
__global__ __launch_bounds__(256, 2) void k_gemm1(
    const f16* __restrict__ xp, const f16* __restrict__ wgu,
    const int* __restrict__ tile_map, f16* __restrict__ hidden) {
    const int b = blockIdx.x;                      // 2304 = 72*32
    const int id = (b & 7) * (NT * 32 / 8) + (b >> 3);
    const int rt = id >> 5, ct = id & 31;
    const int e = tile_map[rt];
    if (e < 0) return;
    const int rbase = rt * 128, cbase = ct * 128;
    const f16* asrc = xp + (size_t)rbase * DMODEL;
    const f16* bsrc = wgu + (size_t)e * NGU * DMODEL + (size_t)cbase * DMODEL;

    GCORE(16, DMODEL)

#pragma unroll
    for (int mf = 0; mf < 4; ++mf) {
#pragma unroll
        for (int pair = 0; pair < 2; ++pair) {
            const int ng = pair * 2, nu = ng + 1;
            const int cblock = cbase + wn * 64 + ng * 16;   // bit4==0: gate
            const int h = ((cblock >> 5) << 4) + lrow;
#pragma unroll
            for (int r = 0; r < 4; ++r) {
                const int row = rbase + wm * 64 + mf * 16 + lk * 4 + r;
                const float g = acc[mf][ng][r], u = acc[mf][nu][r];
                const float hv = g / (1.f + __expf(-g)) * u;
                hidden[(size_t)row * HDIM + h] = (f16)hv;
            }
        }
    }
}

// ---- GEMM2 (hidden @ wd^T) + scatter to out ----
__global__ __launch_bounds__(256, 2) void k_gemm2(
    const f16* __restrict__ hidden, const f16* __restrict__ wd16,
    const int* __restrict__ tile_map, const int* __restrict__ perm,
    float* __restrict__ out) {
    const int b = blockIdx.x;                      // 576 = 72*8
    const int id = (b & 7) * (NT * 8 / 8) + (b >> 3);
    const int rt = id >> 3, ct = id & 7;
    const int e = tile_map[rt];
    if (e < 0) return;
    const int rbase = rt * 128, cbase = ct * 128;
    const f16* asrc = hidden + (size_t)rbase * HDIM;
    const f16* bsrc = wd16 + (size_t)e * DMODEL * HDIM + (size_t)cbase * HDIM;

    GCORE(32, HDIM)

#pragma unroll
    for (int mf = 0; mf < 4; ++mf) {
        int toks[4];
#pragma unroll
        for (int r = 0; r < 4; ++r)
            toks[r] = perm[rbase + wm * 64 + mf * 16 + lk * 4 + r];
#pragma unroll
        for (int n = 0; n < 4; ++n) {
            const int col = cbase + wn * 64 + n * 16 + lrow;
#pragma unroll
            for (int r = 0; r < 4; ++r)
                if (toks[r] >= 0) out[(size_t)toks[r] * DMODEL + col] = acc[mf][n][r];
        }
    }
}

extern "C" void kernel_launch(void* const* d_in, const int* in_sizes, int n_in,
                              void* d_out, int out_size, void* d_ws, size_t ws_size,
                              hipStream_t stream) {
    const float* x = (const float*)d_in[0];
    const float* wg = (const float*)d_in[1];
    const float* wu = (const float*)d_in[2];
    const float* wd = (const float*)d_in[3];
    const int* ids = (const int*)d_in[4];
    float* out = (float*)d_out;

    char* ws = (char*)d_ws;
    int* cursor = (int*)ws;
    int* tile_map = (int*)(ws + 64);
    int* perm = (int*)(ws + 4096);
    const size_t XP_OFF = 65536;
    const size_t XP_BYTES = (size_t)NPAD * DMODEL * 2;          // 18.9 MB
    const size_t HID_OFF = XP_OFF + XP_BYTES;
    const size_t HID_BYTES = (size_t)NPAD * HDIM * 2;           // 37.7 MB
    const size_t WGU_OFF = HID_OFF + HID_BYTES;
    // wd16 aliases wgu (dead after GEMM1); cvt_wd runs after GEMM1.

    f16* xp = (f16*)(ws + XP_OFF);
    f16* hidden = (f16*)(ws + HID_OFF);
    f16* wgu16 = (f16*)(ws + WGU_OFF);
    f16* wd16 = (f16*)(ws + WGU_OFF);

    hipMemsetAsync(perm, 0xFF, (size_t)NPAD * 4, stream);
    k_plan<<<1, 256, 0, stream>>>(ids, cursor, tile_map);
    k_scatter<<<N_TOK / 256, 256, 0, stream>>>(ids, cursor, perm);
    k_gather<<<NPAD, 128, 0, stream>>>(x, perm, xp);
    k_cvt_gu<<<NEXP * NGU, 128, 0, stream>>>(wg, wu, wgu16);
    k_gemm1<<<NT * 32, 256, 0, stream>>>(xp, wgu16, tile_map, hidden);
    k_cvt<<<8192, 256, 0, stream>>>(wd, wd16);
    k_gemm2<<<NT * 8, 256, 0, stream>>>(hidden, wd16, tile_map, perm, out);
}

// Round 6
// 329.311 us; speedup vs baseline: 1.1320x; 1.1320x over previous
//
#include <hip/hip_runtime.h>
#include <hip/hip_fp16.h>

#define N_TOK 8192
#define DMODEL 1024
#define HDIM 2048
#define NEXP 8
#define NGU (2 * HDIM)               // 4096 interleaved gate/up cols
#define NPAD (N_TOK + NEXP * 256)    // 10240 (expert segments padded to x256)
#define NTILES (NPAD / 256)          // 40

typedef _Float16 f16;
typedef _Float16 f16x8 __attribute__((ext_vector_type(8)));
typedef float f32x4 __attribute__((ext_vector_type(4)));

#define SBAR() __builtin_amdgcn_sched_barrier(0)
#define BARRIER() do { __builtin_amdgcn_s_barrier(); SBAR(); } while (0)
#define WAIT_LGKM0() do { asm volatile("s_waitcnt lgkmcnt(0)" ::: "memory"); SBAR(); } while (0)
#define WAIT_VM(n)  do { asm volatile("s_waitcnt vmcnt(" #n ")" ::: "memory"); SBAR(); } while (0)

__device__ __forceinline__ void gload16(const void* g, void* l) {
    __builtin_amdgcn_global_load_lds(
        (const __attribute__((address_space(1))) void*)g,
        (__attribute__((address_space(3))) void*)l, 16, 0, 0);
}

// ---- aux kernels ----
__global__ void k_plan(const int* __restrict__ ids, int* __restrict__ cursor,
                       int* __restrict__ tile_map) {
    __shared__ int hist[NEXP];
    const int tid = threadIdx.x;
    if (tid < NEXP) hist[tid] = 0;
    __syncthreads();
    for (int t = tid; t < N_TOK; t += 256) atomicAdd(&hist[ids[t]], 1);
    __syncthreads();
    if (tid == 0) {
        int pos = 0, tile = 0;
        for (int e = 0; e < NEXP; ++e) {
            cursor[e] = pos;
            const int nt = (hist[e] + 255) >> 8;
            for (int i = 0; i < nt; ++i) tile_map[tile++] = e;
            pos += nt * 256;
        }
        for (; tile < NTILES; ++tile) tile_map[tile] = -1;
    }
}

__global__ void k_scatter(const int* __restrict__ ids, int* __restrict__ cursor,
                          int* __restrict__ perm) {
    const int t = blockIdx.x * 256 + threadIdx.x;
    if (t < N_TOK) {
        const int pos = atomicAdd(&cursor[ids[t]], 1);
        perm[pos] = t;
    }
}

__global__ void k_cvt(const float* __restrict__ src, f16* __restrict__ dst) {
    const size_t i = (size_t)blockIdx.x * 256 + threadIdx.x;
    const float4* s = (const float4*)src + i * 2;
    const float4 a = s[0], b = s[1];
    f16x8 v;
    v[0] = (f16)a.x; v[1] = (f16)a.y; v[2] = (f16)a.z; v[3] = (f16)a.w;
    v[4] = (f16)b.x; v[5] = (f16)b.y; v[6] = (f16)b.z; v[7] = (f16)b.w;
    ((f16x8*)dst)[i] = v;
}

// gate/up -> interleaved f16 [E][4096][1024]; col c: h=(c>>5)*16+(c&15), bit4: up
__global__ void k_cvt_gu(const float* __restrict__ wg, const float* __restrict__ wu,
                         f16* __restrict__ wgu) {
    const int R = blockIdx.x;
    const int e = R >> 12, c = R & (NGU - 1);
    const int h = ((c >> 5) << 4) | (c & 15);
    const float* src = (((c >> 4) & 1) ? wu : wg) + ((size_t)e * HDIM + h) * DMODEL;
    f16* dst = wgu + (size_t)R * DMODEL;
    const int t = threadIdx.x;
    const float4* s = (const float4*)src + t * 2;
    const float4 a = s[0], b = s[1];
    f16x8 v;
    v[0] = (f16)a.x; v[1] = (f16)a.y; v[2] = (f16)a.z; v[3] = (f16)a.w;
    v[4] = (f16)b.x; v[5] = (f16)b.y; v[6] = (f16)b.z; v[7] = (f16)b.w;
    ((f16x8*)dst)[t] = v;
}

__global__ void k_gather(const float* __restrict__ x, const int* __restrict__ perm,
                         f16* __restrict__ xp) {
    const int row = blockIdx.x;
    const int tok = perm[row];
    const int c = threadIdx.x;
    f16x8 v;
#pragma unroll
    for (int j = 0; j < 8; ++j) v[j] = (f16)0.f;
    if (tok >= 0) {
        const float4* s = (const float4*)(x + (size_t)tok * DMODEL) + c * 2;
        const float4 a = s[0], b = s[1];
        v[0] = (f16)a.x; v[1] = (f16)a.y; v[2] = (f16)a.z; v[3] = (f16)a.w;
        v[4] = (f16)b.x; v[5] = (f16)b.y; v[6] = (f16)b.z; v[7] = (f16)b.w;
    }
    *((f16x8*)(xp + (size_t)row * DMODEL) + c) = v;
}

// ======== 256x256 8-phase GEMM core (8 waves, BK=64, dbuf 8 half-slots) ========
// LDS slots: [parity][h] h=0:A0 1:A1 2:B0 3:B1, 16KB each (128 rows x 128B).
// XOR swizzle on 16B slots (row&7), pre-swizzled global src + swizzled ds_read.
// Schedule per kt (phases q=0..3):
//   q0: ds_read B(8)+A(q0); stage A0(kt+1), A1(kt+1)
//   q1: ds_read A(q1); stage B0(kt+2)
//   q2: ds_read A(q2); stage B1(kt+2)
//   q3: ds_read A(q3); vmcnt(4)  [drains everything except B01(kt+2)]
//   each phase: BARRIER; lgkm(0); setprio1; 16 MFMA; setprio0; BARRIER
// Cross-wave safety: every slot's staging loads are vm-drained at the q3
// preceding the kt that reads them (A: 3 phases cover; B: 6 phases).

#define GEMM_CORE(NKT_, STRIDE_)                                                      \
    const int tid = threadIdx.x;                                                      \
    const int lane = tid & 63, wid = tid >> 6;                                        \
    const int wm = wid >> 2, wn = wid & 3;                                            \
    const int lrow = lane & 15, lk = lane >> 4;                                       \
    __shared__ char smem[131072];                                                     \
    const int scol = (lane & 7) ^ (lane >> 3);                                        \
    const int xs0 = ((lk) ^ (lrow & 7)) * 16;                                         \
    const int xs1 = ((4 + lk) ^ (lrow & 7)) * 16;                                     \
    f32x4 acc[8][4] = {};                                                             \
    auto stage = [&](int h, int kt2) {                                                \
        const f16* base = (h < 2) ? (asrc + (size_t)(h * 128) * STRIDE_)              \
                                  : (bsrc + (size_t)((h - 2) * 128) * STRIDE_);       \
        char* dst = smem + ((kt2 & 1) * 4 + h) * 16384 + wid * 1024;                  \
        const int kb = kt2 * 64;                                                      \
        _Pragma("unroll")                                                             \
        for (int pass = 0; pass < 2; ++pass) {                                        \
            const int row = pass * 64 + wid * 8 + (lane >> 3);                        \
            gload16(base + (size_t)row * STRIDE_ + kb + scol * 8, dst + pass * 8192); \
        }                                                                             \
    };                                                                                \
    stage(0, 0); stage(1, 0); stage(2, 0); stage(3, 0);                               \
    stage(2, 1); stage(3, 1);                                                         \
    WAIT_VM(4);                                                                       \
    BARRIER();                                                                        \
    f16x8 b[4][2];                                                                    \
    _Pragma("unroll 1")                                                               \
    for (int kt = 0; kt < NKT_; ++kt) {                                               \
        char* bufA = smem + ((kt & 1) * 4 + wm) * 16384;                              \
        char* bufB = smem + ((kt & 1) * 4 + 2 + (wn >> 1)) * 16384;                   \
        const int brow = (wn & 1) * 64;                                               \
        _Pragma("unroll")                                                             \
        for (int q = 0; q < 4; ++q) {                                                 \
            f16x8 a[2][2];                                                            \
            _Pragma("unroll")                                                         \
            for (int mi = 0; mi < 2; ++mi) {                                          \
                const int r = q * 32 + mi * 16 + lrow;                                \
                a[mi][0] = *(const f16x8*)(bufA + r * 128 + xs0);                     \
                a[mi][1] = *(const f16x8*)(bufA + r * 128 + xs1);                     \
            }                                                                         \
            if (q == 0) {                                                             \
                _Pragma("unroll")                                                     \
                for (int n = 0; n < 4; ++n) {                                         \
                    const int r = brow + n * 16 + lrow;                               \
                    b[n][0] = *(const f16x8*)(bufB + r * 128 + xs0);                  \
                    b[n][1] = *(const f16x8*)(bufB + r * 128 + xs1);                  \
                }                                                                     \
            }                                                                         \
            if (q == 0 && kt + 1 < NKT_) { stage(0, kt + 1); stage(1, kt + 1); }      \
            if (q == 1 && kt + 2 < NKT_) stage(2, kt + 2);                            \
            if (q == 2 && kt + 2 < NKT_) stage(3, kt + 2);                            \
            if (q == 3) {                                                             \
                if (kt + 2 < NKT_) { WAIT_VM(4); } else { WAIT_VM(0); }               \
            }                                                                         \
            BARRIER();                                                                \
            WAIT_LGKM0();                                                             \
            __builtin_amdgcn_s_setprio(1);                                            \
            _Pragma("unroll")                                                         \
            for (int mi = 0; mi < 2; ++mi)                                            \
                _Pragma("unroll")                                                     \
                for (int n = 0; n < 4; ++n) {                                         \
                    acc[q * 2 + mi][n] = __builtin_amdgcn_mfma_f32_16x16x32_f16(      \
                        a[mi][0], b[n][0], acc[q * 2 + mi][n], 0, 0, 0);              \
                    acc[q * 2 + mi][n] = __builtin_amdgcn_mfma_f32_16x16x32_f16(      \
                        a[mi][1], b[n][1], acc[q * 2 + mi][n], 0, 0, 0);              \
                }                                                                     \
            __builtin_amdgcn_s_setprio(0);                                            \
            BARRIER();                                                                \
        }                                                                             \
    }

// ---- GEMM1 (xp @ wgu^T) + SwiGLU -> hidden ----
__global__ __launch_bounds__(512, 2) void k_gemm1(
    const f16* __restrict__ xp, const f16* __restrict__ wgu,
    const int* __restrict__ tile_map, f16* __restrict__ hidden) {
    // 640 blocks; XCD k owns 2 contiguous ct columns (rt-major within column)
    const int bid = blockIdx.x;
    const int g = (bid & 7) * 80 + (bid >> 3);
    const int ct = g / NTILES, rt = g % NTILES;
    const int e = tile_map[rt];
    if (e < 0) return;
    const int rbase = rt * 256, cbase = ct * 256;
    const f16* asrc = xp + (size_t)rbase * DMODEL;
    const f16* bsrc = wgu + (size_t)e * NGU * DMODEL + (size_t)cbase * DMODEL;

    GEMM_CORE(16, DMODEL)

    // epilogue: pair (gate,up) frags -> silu(g)*u -> hidden f16
#pragma unroll
    for (int mf = 0; mf < 8; ++mf) {
#pragma unroll
        for (int pair = 0; pair < 2; ++pair) {
            const int ng = pair * 2, nu = ng + 1;
            const int cblock = cbase + wn * 64 + ng * 16;   // bit4==0: gate
            const int h = ((cblock >> 5) << 4) + lrow;
#pragma unroll
            for (int r = 0; r < 4; ++r) {
                const int row = rbase + wm * 128 + mf * 16 + lk * 4 + r;
                const float gg = acc[mf][ng][r], uu = acc[mf][nu][r];
                const float hv = gg / (1.f + __expf(-gg)) * uu;
                hidden[(size_t)row * HDIM + h] = (f16)hv;
            }
        }
    }
}

// ---- GEMM2 (hidden @ wd^T) split-K=2 + atomic scatter to out ----
__global__ __launch_bounds__(512, 2) void k_gemm2(
    const f16* __restrict__ hidden, const f16* __restrict__ wd16,
    const int* __restrict__ tile_map, const int* __restrict__ perm,
    float* __restrict__ out) {
    // 320 blocks; g = (s, ct, rt); XCD k owns one (s,ct) column of 40 rt
    const int bid = blockIdx.x;
    const int g = (bid & 7) * 40 + (bid >> 3);
    const int s = g / 160;
    const int rem = g % 160;
    const int ct = rem / NTILES, rt = rem % NTILES;
    const int e = tile_map[rt];
    if (e < 0) return;
    const int rbase = rt * 256, cbase = ct * 256;
    const f16* asrc = hidden + (size_t)rbase * HDIM + s * 1024;
    const f16* bsrc = wd16 + (size_t)e * DMODEL * HDIM + (size_t)cbase * HDIM + s * 1024;

    GEMM_CORE(16, HDIM)

    // epilogue: atomic add (2 commutative partials, deterministic) to token rows
#pragma unroll
    for (int mf = 0; mf < 8; ++mf) {
        int toks[4];
#pragma unroll
        for (int r = 0; r < 4; ++r)
            toks[r] = perm[rbase + wm * 128 + mf * 16 + lk * 4 + r];
#pragma unroll
        for (int n = 0; n < 4; ++n) {
            const int col = cbase + wn * 64 + n * 16 + lrow;
#pragma unroll
            for (int r = 0; r < 4; ++r)
                if (toks[r] >= 0)
                    unsafeAtomicAdd(&out[(size_t)toks[r] * DMODEL + col], acc[mf][n][r]);
        }
    }
}

extern "C" void kernel_launch(void* const* d_in, const int* in_sizes, int n_in,
                              void* d_out, int out_size, void* d_ws, size_t ws_size,
                              hipStream_t stream) {
    const float* x = (const float*)d_in[0];
    const float* wg = (const float*)d_in[1];
    const float* wu = (const float*)d_in[2];
    const float* wd = (const float*)d_in[3];
    const int* ids = (const int*)d_in[4];
    float* out = (float*)d_out;

    char* ws = (char*)d_ws;
    int* cursor = (int*)ws;
    int* tile_map = (int*)(ws + 64);
    int* perm = (int*)(ws + 4096);
    const size_t XP_OFF = 65536;
    const size_t XP_BYTES = (size_t)NPAD * DMODEL * 2;          // 21.0 MB
    const size_t HID_OFF = XP_OFF + XP_BYTES;
    const size_t HID_BYTES = (size_t)NPAD * HDIM * 2;           // 41.9 MB
    const size_t WGU_OFF = HID_OFF + HID_BYTES;
    // wd16 aliases wgu (dead after GEMM1); cvt_wd runs after GEMM1.

    f16* xp = (f16*)(ws + XP_OFF);
    f16* hidden = (f16*)(ws + HID_OFF);
    f16* wgu16 = (f16*)(ws + WGU_OFF);
    f16* wd16 = (f16*)(ws + WGU_OFF);

    hipMemsetAsync(perm, 0xFF, (size_t)NPAD * 4, stream);
    hipMemsetAsync(out, 0, (size_t)out_size * 4, stream);
    k_plan<<<1, 256, 0, stream>>>(ids, cursor, tile_map);
    k_scatter<<<N_TOK / 256, 256, 0, stream>>>(ids, cursor, perm);
    k_gather<<<NPAD, 128, 0, stream>>>(x, perm, xp);
    k_cvt_gu<<<NEXP * NGU, 128, 0, stream>>>(wg, wu, wgu16);
    k_gemm1<<<NTILES * 16, 512, 0, stream>>>(xp, wgu16, tile_map, hidden);
    k_cvt<<<8192, 256, 0, stream>>>(wd, wd16);
    k_gemm2<<<NTILES * 8, 512, 0, stream>>>(hidden, wd16, tile_map, perm, out);
}

// Round 7
// 283.849 us; speedup vs baseline: 1.3133x; 1.1602x over previous
//
#include <hip/hip_runtime.h>
#include <hip/hip_fp16.h>

#define N_TOK 8192
#define DMODEL 1024
#define HDIM 2048
#define NEXP 8
#define NGU (2 * HDIM)               // 4096 interleaved gate/up cols
#define NPAD (N_TOK + NEXP * 256)    // 10240 (expert segments padded to x256)
#define NTILES (NPAD / 256)          // 40 (256-row tiles, GEMM1)
#define NT2 (2 * NTILES)             // 80 (128-row tiles, GEMM2)

typedef _Float16 f16;
typedef _Float16 f16x8 __attribute__((ext_vector_type(8)));
typedef float f32x4 __attribute__((ext_vector_type(4)));

#define SBAR() __builtin_amdgcn_sched_barrier(0)
#define BARRIER() do { __builtin_amdgcn_s_barrier(); SBAR(); } while (0)
#define WAIT_LGKM0() do { asm volatile("s_waitcnt lgkmcnt(0)" ::: "memory"); SBAR(); } while (0)
#define WAIT_VM(n)  do { asm volatile("s_waitcnt vmcnt(" #n ")" ::: "memory"); SBAR(); } while (0)

__device__ __forceinline__ void gload16(const void* g, void* l) {
    __builtin_amdgcn_global_load_lds(
        (const __attribute__((address_space(1))) void*)g,
        (__attribute__((address_space(3))) void*)l, 16, 0, 0);
}

// ---- aux kernels ----
__global__ void k_plan(const int* __restrict__ ids, int* __restrict__ cursor,
                       int* __restrict__ tile_map, int* __restrict__ tile_map2) {
    __shared__ int hist[NEXP];
    const int tid = threadIdx.x;
    if (tid < NEXP) hist[tid] = 0;
    __syncthreads();
    for (int t = tid; t < N_TOK; t += 256) atomicAdd(&hist[ids[t]], 1);
    __syncthreads();
    if (tid == 0) {
        int pos = 0, tile = 0;
        for (int e = 0; e < NEXP; ++e) {
            cursor[e] = pos;
            const int nt = (hist[e] + 255) >> 8;
            for (int i = 0; i < nt; ++i) tile_map[tile++] = e;
            pos += nt * 256;
        }
        for (; tile < NTILES; ++tile) tile_map[tile] = -1;
        for (int t = 0; t < NTILES; ++t) {
            tile_map2[2 * t] = tile_map[t];
            tile_map2[2 * t + 1] = tile_map[t];
        }
    }
}

__global__ void k_scatter(const int* __restrict__ ids, int* __restrict__ cursor,
                          int* __restrict__ perm) {
    const int t = blockIdx.x * 256 + threadIdx.x;
    if (t < N_TOK) {
        const int pos = atomicAdd(&cursor[ids[t]], 1);
        perm[pos] = t;
    }
}

__global__ void k_cvt(const float* __restrict__ src, f16* __restrict__ dst) {
    const size_t i = (size_t)blockIdx.x * 256 + threadIdx.x;
    const float4* s = (const float4*)src + i * 2;
    const float4 a = s[0], b = s[1];
    f16x8 v;
    v[0] = (f16)a.x; v[1] = (f16)a.y; v[2] = (f16)a.z; v[3] = (f16)a.w;
    v[4] = (f16)b.x; v[5] = (f16)b.y; v[6] = (f16)b.z; v[7] = (f16)b.w;
    ((f16x8*)dst)[i] = v;
}

// gate/up -> interleaved f16 [E][4096][1024]; col c: h=(c>>5)*16+(c&15), bit4: up
__global__ void k_cvt_gu(const float* __restrict__ wg, const float* __restrict__ wu,
                         f16* __restrict__ wgu) {
    const int R = blockIdx.x;
    const int e = R >> 12, c = R & (NGU - 1);
    const int h = ((c >> 5) << 4) | (c & 15);
    const float* src = (((c >> 4) & 1) ? wu : wg) + ((size_t)e * HDIM + h) * DMODEL;
    f16* dst = wgu + (size_t)R * DMODEL;
    const int t = threadIdx.x;
    const float4* s = (const float4*)src + t * 2;
    const float4 a = s[0], b = s[1];
    f16x8 v;
    v[0] = (f16)a.x; v[1] = (f16)a.y; v[2] = (f16)a.z; v[3] = (f16)a.w;
    v[4] = (f16)b.x; v[5] = (f16)b.y; v[6] = (f16)b.z; v[7] = (f16)b.w;
    ((f16x8*)dst)[t] = v;
}

__global__ void k_gather(const float* __restrict__ x, const int* __restrict__ perm,
                         f16* __restrict__ xp) {
    const int row = blockIdx.x;
    const int tok = perm[row];
    const int c = threadIdx.x;
    f16x8 v;
#pragma unroll
    for (int j = 0; j < 8; ++j) v[j] = (f16)0.f;
    if (tok >= 0) {
        const float4* s = (const float4*)(x + (size_t)tok * DMODEL) + c * 2;
        const float4 a = s[0], b = s[1];
        v[0] = (f16)a.x; v[1] = (f16)a.y; v[2] = (f16)a.z; v[3] = (f16)a.w;
        v[4] = (f16)b.x; v[5] = (f16)b.y; v[6] = (f16)b.z; v[7] = (f16)b.w;
    }
    *((f16x8*)(xp + (size_t)row * DMODEL) + c) = v;
}

// ======== GEMM1: 256x256 8-phase core (round-4 exact; best measured) ========
#define GEMM_CORE(NKT_, STRIDE_)                                                      \
    const int tid = threadIdx.x;                                                      \
    const int lane = tid & 63, wid = tid >> 6;                                        \
    const int wm = wid >> 2, wn = wid & 3;                                            \
    const int lrow = lane & 15, lk = lane >> 4;                                       \
    __shared__ char smem[131072];                                                     \
    const int scol = (lane & 7) ^ (lane >> 3);                                        \
    const int xs0 = ((lk) ^ (lrow & 7)) * 16;                                         \
    const int xs1 = ((4 + lk) ^ (lrow & 7)) * 16;                                     \
    f32x4 acc[8][4] = {};                                                             \
    auto stage = [&](int h, int kt2) {                                                \
        const f16* base = (h < 2) ? (asrc + (size_t)(h * 128) * STRIDE_)              \
                                  : (bsrc + (size_t)((h - 2) * 128) * STRIDE_);       \
        char* dst = smem + ((kt2 & 1) * 4 + h) * 16384 + wid * 1024;                  \
        const int kb = kt2 * 64;                                                      \
        _Pragma("unroll")                                                             \
        for (int pass = 0; pass < 2; ++pass) {                                        \
            const int row = pass * 64 + wid * 8 + (lane >> 3);                        \
            gload16(base + (size_t)row * STRIDE_ + kb + scol * 8, dst + pass * 8192); \
        }                                                                             \
    };                                                                                \
    stage(0, 0); stage(1, 0); stage(2, 0); stage(3, 0);                               \
    stage(2, 1); stage(3, 1);                                                         \
    WAIT_VM(4);                                                                       \
    BARRIER();                                                                        \
    f16x8 b[4][2];                                                                    \
    _Pragma("unroll 1")                                                               \
    for (int kt = 0; kt < NKT_; ++kt) {                                               \
        char* bufA = smem + ((kt & 1) * 4 + wm) * 16384;                              \
        char* bufB = smem + ((kt & 1) * 4 + 2 + (wn >> 1)) * 16384;                   \
        const int brow = (wn & 1) * 64;                                               \
        _Pragma("unroll")                                                             \
        for (int q = 0; q < 4; ++q) {                                                 \
            f16x8 a[2][2];                                                            \
            _Pragma("unroll")                                                         \
            for (int mi = 0; mi < 2; ++mi) {                                          \
                const int r = q * 32 + mi * 16 + lrow;                                \
                a[mi][0] = *(const f16x8*)(bufA + r * 128 + xs0);                     \
                a[mi][1] = *(const f16x8*)(bufA + r * 128 + xs1);                     \
            }                                                                         \
            if (q == 0) {                                                             \
                _Pragma("unroll")                                                     \
                for (int n = 0; n < 4; ++n) {                                         \
                    const int r = brow + n * 16 + lrow;                               \
                    b[n][0] = *(const f16x8*)(bufB + r * 128 + xs0);                  \
                    b[n][1] = *(const f16x8*)(bufB + r * 128 + xs1);                  \
                }                                                                     \
            }                                                                         \
            if (q == 0 && kt + 1 < NKT_) stage(0, kt + 1);                            \
            if (q == 1 && kt + 1 < NKT_) stage(1, kt + 1);                            \
            if (q == 2 && kt + 2 < NKT_) stage(2, kt + 2);                            \
            if (q == 3) {                                                             \
                if (kt + 2 < NKT_) { WAIT_VM(2); stage(3, kt + 2); }                  \
                else { WAIT_VM(0); }                                                  \
            }                                                                         \
            BARRIER();                                                                \
            WAIT_LGKM0();                                                             \
            __builtin_amdgcn_s_setprio(1);                                            \
            _Pragma("unroll")                                                         \
            for (int mi = 0; mi < 2; ++mi)                                            \
                _Pragma("unroll")                                                     \
                for (int n = 0; n < 4; ++n) {                                         \
                    acc[q * 2 + mi][n] = __builtin_amdgcn_mfma_f32_16x16x32_f16(      \
                        a[mi][0], b[n][0], acc[q * 2 + mi][n], 0, 0, 0);              \
                    acc[q * 2 + mi][n] = __builtin_amdgcn_mfma_f32_16x16x32_f16(      \
                        a[mi][1], b[n][1], acc[q * 2 + mi][n], 0, 0, 0);              \
                }                                                                     \
            __builtin_amdgcn_s_setprio(0);                                            \
            BARRIER();                                                                \
        }                                                                             \
    }

// ---- GEMM1 (xp @ wgu^T) + SwiGLU -> hidden ----
__global__ __launch_bounds__(512, 2) void k_gemm1(
    const f16* __restrict__ xp, const f16* __restrict__ wgu,
    const int* __restrict__ tile_map, f16* __restrict__ hidden) {
    const int rt = blockIdx.y, ct = blockIdx.x;
    const int e = tile_map[rt];
    if (e < 0) return;
    const int rbase = rt * 256, cbase = ct * 256;
    const f16* asrc = xp + (size_t)rbase * DMODEL;
    const f16* bsrc = wgu + (size_t)e * NGU * DMODEL + (size_t)cbase * DMODEL;

    GEMM_CORE(16, DMODEL)

    // epilogue: pair (gate,up) frags -> silu(g)*u -> hidden f16
#pragma unroll
    for (int mf = 0; mf < 8; ++mf) {
#pragma unroll
        for (int pair = 0; pair < 2; ++pair) {
            const int ng = pair * 2, nu = ng + 1;
            const int cblock = cbase + wn * 64 + ng * 16;   // bit4==0: gate
            const int h = ((cblock >> 5) << 4) + lrow;
#pragma unroll
            for (int r = 0; r < 4; ++r) {
                const int row = rbase + wm * 128 + mf * 16 + lk * 4 + r;
                const float gg = acc[mf][ng][r], uu = acc[mf][nu][r];
                const float hv = gg / (1.f + __expf(-gg)) * uu;
                hidden[(size_t)row * HDIM + h] = (f16)hv;
            }
        }
    }
}

// ======== GEMM2: 128x128, 4 waves, 64KB LDS (2 blocks/CU), 2-phase vmcnt(8) ====
__global__ __launch_bounds__(256, 2) void k_gemm2(
    const f16* __restrict__ hidden, const f16* __restrict__ wd16,
    const int* __restrict__ tile_map2, const int* __restrict__ perm,
    float* __restrict__ out) {
    const int rt = blockIdx.y, ct = blockIdx.x;   // rt: 80 (128-row), ct: 8
    const int e = tile_map2[rt];
    if (e < 0) return;
    const int tid = threadIdx.x;
    const int lane = tid & 63, wid = tid >> 6;    // 4 waves
    const int wm = wid >> 1, wn = wid & 1;
    const int lrow = lane & 15, lk = lane >> 4;
    const int rbase = rt * 128, cbase = ct * 128;
    const f16* asrc = hidden + (size_t)rbase * HDIM;
    const f16* bsrc = wd16 + (size_t)e * DMODEL * HDIM + (size_t)cbase * HDIM;

    __shared__ char smem[65536];   // A dbuf 2x16KB @0, B dbuf 2x16KB @32768
    const int scol = (lane & 7) ^ (lane >> 3);

    // stage both 128x64 tiles of kt2 (8 gloads/wave: 4 A + 4 B)
    auto stage2 = [&](int kt2) {
        char* dA = smem + (kt2 & 1) * 16384;
        char* dB = smem + 32768 + (kt2 & 1) * 16384;
        const int kb = kt2 * 64;
#pragma unroll
        for (int i = 0; i < 4; ++i) {
            const int chunk = wid * 4 + i;            // 16 chunks x 1KB (8 rows)
            const int row = chunk * 8 + (lane >> 3);
            gload16(asrc + (size_t)row * HDIM + kb + scol * 8, dA + chunk * 1024);
        }
#pragma unroll
        for (int i = 0; i < 4; ++i) {
            const int chunk = wid * 4 + i;
            const int row = chunk * 8 + (lane >> 3);
            gload16(bsrc + (size_t)row * HDIM + kb + scol * 8, dB + chunk * 1024);
        }
    };

    int off_a[4][2], off_b[4][2];
#pragma unroll
    for (int f = 0; f < 4; ++f) {
        const int ra = wm * 64 + f * 16 + lrow;
        const int rb = wn * 64 + f * 16 + lrow;
#pragma unroll
        for (int kk = 0; kk < 2; ++kk) {
            off_a[f][kk] = ra * 128 + (((kk * 4 + lk) ^ (ra & 7)) * 16);
            off_b[f][kk] = rb * 128 + (((kk * 4 + lk) ^ (rb & 7)) * 16);
        }
    }

    f32x4 acc[4][4] = {};
    stage2(0);
    _Pragma("unroll 1")
    for (int kt = 0; kt < 32; ++kt) {
        if (kt + 1 < 32) { stage2(kt + 1); WAIT_VM(8); }
        else { WAIT_VM(0); }
        BARRIER();                       // all waves' kt tiles resident
        char* bA = smem + (kt & 1) * 16384;
        char* bB = smem + 32768 + (kt & 1) * 16384;
        f16x8 a[4][2], b[4][2];
#pragma unroll
        for (int f = 0; f < 4; ++f) {
#pragma unroll
            for (int kk = 0; kk < 2; ++kk) {
                a[f][kk] = *(const f16x8*)(bA + off_a[f][kk]);
                b[f][kk] = *(const f16x8*)(bB + off_b[f][kk]);
            }
        }
        WAIT_LGKM0();
        __builtin_amdgcn_s_setprio(1);
#pragma unroll
        for (int m = 0; m < 4; ++m)
#pragma unroll
            for (int n = 0; n < 4; ++n) {
                acc[m][n] = __builtin_amdgcn_mfma_f32_16x16x32_f16(a[m][0], b[n][0], acc[m][n], 0, 0, 0);
                acc[m][n] = __builtin_amdgcn_mfma_f32_16x16x32_f16(a[m][1], b[n][1], acc[m][n], 0, 0, 0);
            }
        __builtin_amdgcn_s_setprio(0);
        BARRIER();                       // reads done before next overwrite
    }

    // epilogue: direct scatter to token rows (fp32)
#pragma unroll
    for (int mf = 0; mf < 4; ++mf) {
        int toks[4];
#pragma unroll
        for (int r = 0; r < 4; ++r)
            toks[r] = perm[rbase + wm * 64 + mf * 16 + lk * 4 + r];
#pragma unroll
        for (int n = 0; n < 4; ++n) {
            const int col = cbase + wn * 64 + n * 16 + lrow;
#pragma unroll
            for (int r = 0; r < 4; ++r)
                if (toks[r] >= 0) out[(size_t)toks[r] * DMODEL + col] = acc[mf][n][r];
        }
    }
}

extern "C" void kernel_launch(void* const* d_in, const int* in_sizes, int n_in,
                              void* d_out, int out_size, void* d_ws, size_t ws_size,
                              hipStream_t stream) {
    const float* x = (const float*)d_in[0];
    const float* wg = (const float*)d_in[1];
    const float* wu = (const float*)d_in[2];
    const float* wd = (const float*)d_in[3];
    const int* ids = (const int*)d_in[4];
    float* out = (float*)d_out;

    char* ws = (char*)d_ws;
    int* cursor = (int*)ws;
    int* tile_map = (int*)(ws + 64);
    int* tile_map2 = (int*)(ws + 512);
    int* perm = (int*)(ws + 4096);
    const size_t XP_OFF = 65536;
    const size_t XP_BYTES = (size_t)NPAD * DMODEL * 2;          // 21.0 MB
    const size_t HID_OFF = XP_OFF + XP_BYTES;
    const size_t HID_BYTES = (size_t)NPAD * HDIM * 2;           // 41.9 MB
    const size_t WGU_OFF = HID_OFF + HID_BYTES;
    // wd16 aliases wgu (dead after GEMM1); cvt_wd runs after GEMM1.

    f16* xp = (f16*)(ws + XP_OFF);
    f16* hidden = (f16*)(ws + HID_OFF);
    f16* wgu16 = (f16*)(ws + WGU_OFF);
    f16* wd16 = (f16*)(ws + WGU_OFF);

    hipMemsetAsync(perm, 0xFF, (size_t)NPAD * 4, stream);
    k_plan<<<1, 256, 0, stream>>>(ids, cursor, tile_map, tile_map2);
    k_scatter<<<N_TOK / 256, 256, 0, stream>>>(ids, cursor, perm);
    k_gather<<<NPAD, 128, 0, stream>>>(x, perm, xp);
    k_cvt_gu<<<NEXP * NGU, 128, 0, stream>>>(wg, wu, wgu16);
    k_gemm1<<<dim3(NGU / 256, NTILES), 512, 0, stream>>>(xp, wgu16, tile_map, hidden);
    k_cvt<<<8192, 256, 0, stream>>>(wd, wd16);
    k_gemm2<<<dim3(DMODEL / 128, NT2), 256, 0, stream>>>(hidden, wd16, tile_map2, perm, out);
}